// Round 9
// baseline (300.793 us; speedup 1.0000x reference)
//
#include <hip/hip_runtime.h>

#define BB 2
#define SS 2048
#define EE 1024
#define HH 16
#define DD_ 64
#define BH (BB*HH)
#define NQKV (3*EE)
#define MROWS (BB*SS)

typedef _Float16 f16;
typedef _Float16 f16x8 __attribute__((ext_vector_type(8)));
typedef _Float16 f16x4 __attribute__((ext_vector_type(4)));
typedef float f32x4 __attribute__((ext_vector_type(4)));
typedef float f32x16 __attribute__((ext_vector_type(16)));

#define MFMA16(a,b,c) __builtin_amdgcn_mfma_f32_16x16x32_f16(a,b,c,0,0,0)
#define MFMA32(a,b,c) __builtin_amdgcn_mfma_f32_32x32x16_f16(a,b,c,0,0,0)
#define EXP2F(x) __builtin_amdgcn_exp2f(x)
#define LOG2E 1.44269504088896f

__device__ __forceinline__ void gload16(const void* g, void* l) {
    __builtin_amdgcn_global_load_lds(
        (const __attribute__((address_space(1))) void*)g,
        (__attribute__((address_space(3))) void*)l, 16, 0, 0);
}

// ---------------------------------------------------------------------------
// fp32 -> f16 one-shot convert: x (4M), qkv_w (3M), out_w (1M) floats.
// ---------------------------------------------------------------------------
#define NX4  1048576
#define NW14  786432
#define NW24  262144
__global__ __launch_bounds__(256) void cvt_kernel(
    const float* __restrict__ x, const float* __restrict__ w1,
    const float* __restrict__ w2, f16* __restrict__ x16,
    f16* __restrict__ w116, f16* __restrict__ w216)
{
    const int i = blockIdx.x * 256 + threadIdx.x;
    const float* src; f16* dst; int off;
    if (i < NX4)              { src = x;  dst = x16;  off = i; }
    else if (i < NX4 + NW14)  { src = w1; dst = w116; off = i - NX4; }
    else                      { src = w2; dst = w216; off = i - NX4 - NW14; }
    float4 v = ((const float4*)src)[off];
    f16x4 h = { (f16)v.x, (f16)v.y, (f16)v.z, (f16)v.w };
    *(f16x4*)(dst + 4*(size_t)off) = h;
}

// ---------------------------------------------------------------------------
// QKV GEMM, f16 MFMA 16x16x32, 128x128 tile, BK=64, 4 waves.
// ---------------------------------------------------------------------------
__global__ __launch_bounds__(256) void qkv_gemm_kernel(
    const f16* __restrict__ x, const f16* __restrict__ w,
    const float* __restrict__ bias, const float* __restrict__ gates,
    const float* __restrict__ imp, const float* __restrict__ thr,
    f16* __restrict__ q16, f16* __restrict__ k16, f16* __restrict__ v16)
{
    __shared__ f16 As[128*64];
    __shared__ f16 Bs[128*64];
    const int tid  = threadIdx.x;
    const int wave = tid >> 6, lane = tid & 63;
    const int quad = lane >> 4, l15 = lane & 15;
    const int wm = wave & 1, wn = wave >> 1;
    const int m0 = blockIdx.y << 7, n0 = blockIdx.x << 7;

    f32x4 acc[4][4];
#pragma unroll
    for (int i = 0; i < 4; ++i)
#pragma unroll
        for (int j = 0; j < 4; ++j) acc[i][j] = (f32x4){0.f,0.f,0.f,0.f};

    for (int k0 = 0; k0 < EE; k0 += 64) {
        __syncthreads();
#pragma unroll
        for (int u = 0; u < 4; ++u) {
            const int s = tid + (u << 8);
            const int r = s >> 3;
            const int sc = ((s & 7) ^ (r & 7)) << 3;
            gload16(x + (size_t)(m0 + r)*EE + k0 + sc, &As[s << 3]);
            gload16(w + (size_t)(n0 + r)*EE + k0 + sc, &Bs[s << 3]);
        }
        __syncthreads();
#pragma unroll
        for (int ks = 0; ks < 2; ++ks) {
            f16x8 af[4], bf[4];
#pragma unroll
            for (int i = 0; i < 4; ++i) {
                const int r = wm*64 + i*16 + l15;
                af[i] = *(const f16x8*)&As[(r << 6) + ((((ks<<2)+quad) ^ (l15 & 7)) << 3)];
            }
#pragma unroll
            for (int j = 0; j < 4; ++j) {
                const int r = wn*64 + j*16 + l15;
                bf[j] = *(const f16x8*)&Bs[(r << 6) + ((((ks<<2)+quad) ^ (l15 & 7)) << 3)];
            }
#pragma unroll
            for (int i = 0; i < 4; ++i)
#pragma unroll
                for (int j = 0; j < 4; ++j)
                    acc[i][j] = MFMA16(af[i], bf[j], acc[i][j]);
        }
    }

    const int nb    = n0 + wn * 64;
    const int which = nb >> 10;
    const int h     = (nb & 1023) >> 6;
    const float gs   = 1.f / (1.f + __expf(-gates[h] * imp[h]));
    float scale = (gs > thr[0]) ? 1.f : 0.f;
    if (which == 0) scale *= LOG2E;
    f16* __restrict__ dst = (which == 0) ? q16 : ((which == 1) ? k16 : v16);
    float bv[4];
#pragma unroll
    for (int j = 0; j < 4; ++j) bv[j] = bias[nb + j*16 + l15];
#pragma unroll
    for (int i = 0; i < 4; ++i) {
#pragma unroll
        for (int reg = 0; reg < 4; ++reg) {
            const int m = m0 + wm*64 + i*16 + quad*4 + reg;
            const int b = m >> 11, s = m & (SS - 1);
            f16* rowp = dst + (((size_t)(b*HH + h))*SS + s)*DD_ + l15;
#pragma unroll
            for (int j = 0; j < 4; ++j)
                rowp[j*16] = (f16)((acc[i][j][reg] + bv[j]) * scale);
        }
    }
}

// ---------------------------------------------------------------------------
// v transpose [B,H,S,D] -> [B,H,D,S] f16, + vmean (fp32 atomic partials)
// ---------------------------------------------------------------------------
__global__ __launch_bounds__(256) void vtrans_kernel(
    const f16* __restrict__ v16, f16* __restrict__ vt, float* __restrict__ vmean)
{
    __shared__ f16 T[64][74];
    const int tid = threadIdx.x;
    const int bh = blockIdx.y, s0 = blockIdx.x << 6;
#pragma unroll
    for (int u = 0; u < 2; ++u) {
        const int f = tid + (u << 8);
        const int r = f >> 3, c = (f & 7) << 3;
        *(f16x8*)&T[r][c] = *(const f16x8*)(v16 + ((size_t)bh*SS + s0 + r)*DD_ + c);
    }
    __syncthreads();
    const int d = tid >> 2, ch = (tid & 3) << 4;
    union { f16 h[16]; f16x8 v8[2]; } t;
    float ps = 0.f;
#pragma unroll
    for (int u = 0; u < 16; ++u) { f16 val = T[ch + u][d]; t.h[u] = val; ps += (float)val; }
    f16* dp = vt + ((size_t)bh*DD_ + d)*SS + s0 + ch;
    *(f16x8*)(dp)     = t.v8[0];
    *(f16x8*)(dp + 8) = t.v8[1];
    ps += __shfl_xor(ps, 1, 64);
    ps += __shfl_xor(ps, 2, 64);
    if ((tid & 3) == 0) atomicAdd(vmean + bh*DD_ + d, ps * (1.f / SS));
}

// ---------------------------------------------------------------------------
// Flash attention v4: BARRIER-FREE. K and V^T fragments loaded directly from
// global (L1/L2-resident; XCD swizzle keeps each XCD's 4 heads = 2MB in its
// private L2). No Ks/Vs LDS, no __syncthreads. LDS only for the per-wave P
// round-trip (in-wave RAW). 256 thr = 4 waves x 32 q-rows; 512 blocks.
// Base-2 softmax with wave-uniform running max (r6 math, absmax-verified).
// ---------------------------------------------------------------------------
__global__ __launch_bounds__(256) void attn_kernel(
    const f16* __restrict__ q16, const f16* __restrict__ k16,
    const f16* __restrict__ vt, const float* __restrict__ vmean,
    f16* __restrict__ aout)
{
    __shared__ f16 Ps[4][32*64];       // per-wave P [qrow][key], swizzled
    const int tid  = threadIdx.x;
    const int wave = tid >> 6, lane = tid & 63;
    const int l31 = lane & 31, hi = lane >> 5, l7 = lane & 7;

    // XCD swizzle: 512 blocks; 4 heads per XCD
    const int id  = blockIdx.x;
    const int xcd = id & 7, lid = id >> 3;          // lid 0..63
    const int bh  = (xcd << 2) | (lid & 3);
    const int q0  = (lid >> 2) << 7;                // 16 chunks of 128 q-rows

    const f16* qb = q16 + (size_t)bh * SS * DD_;
    const f16* kb = k16 + (size_t)bh * SS * DD_;
    const f16* vb = vt  + (size_t)bh * DD_ * SS;

    // Q frags (B-operand): B[k=ks*16+hi*8+j][n=qrow=l31]
    f16x8 qf[4];
#pragma unroll
    for (int ks = 0; ks < 4; ++ks)
        qf[ks] = *(const f16x8*)(qb + (size_t)(q0 + wave*32 + l31)*DD_ + ks*16 + hi*8);

    f32x16 accO[2];
#pragma unroll
    for (int dt = 0; dt < 2; ++dt)
#pragma unroll
        for (int r = 0; r < 16; ++r) accO[dt][r] = 0.f;
    float M = -1.0e30f, lsum = 0.f;

    // direct-from-global fragment base pointers (advance per k-tile)
    const f16* kp  = kb + (size_t)l31 * DD_ + hi*8;       // K[key=l31(+32)][d..]
    const f16* vp0 = vb + (size_t)l31 * SS + hi*8;        // V^T[d=l31][key..]
    const f16* vp1 = vb + (size_t)(32 + l31) * SS + hi*8; // V^T[d=32+l31][key..]

    for (int kt = 0; kt < SS; kt += 64) {
        // S^T[key][qrow]: A = K rows (direct global), B = Q^T
        f32x16 accS[2];
#pragma unroll
        for (int mt = 0; mt < 2; ++mt)
#pragma unroll
            for (int r = 0; r < 16; ++r) accS[mt][r] = 0.f;
#pragma unroll
        for (int ks = 0; ks < 4; ++ks)
#pragma unroll
            for (int mt = 0; mt < 2; ++mt) {
                f16x8 kf = *(const f16x8*)(kp + mt*32*DD_ + ks*16);
                accS[mt] = MFMA32(kf, qf[ks], accS[mt]);
            }

        // wave-uniform tile max, butterfly over 64 lanes
        float mx = -1.0e30f;
#pragma unroll
        for (int mt = 0; mt < 2; ++mt)
#pragma unroll
            for (int r = 0; r < 16; ++r) mx = fmaxf(mx, accS[mt][r]);
        mx = fmaxf(mx, __shfl_xor(mx, 1, 64));
        mx = fmaxf(mx, __shfl_xor(mx, 2, 64));
        mx = fmaxf(mx, __shfl_xor(mx, 4, 64));
        mx = fmaxf(mx, __shfl_xor(mx, 8, 64));
        mx = fmaxf(mx, __shfl_xor(mx, 16, 64));
        mx = fmaxf(mx, __shfl_xor(mx, 32, 64));
        const float mnew = fmaxf(M, mx);
        const float alpha = EXP2F(M - mnew);
        M = mnew;
        lsum *= alpha;
#pragma unroll
        for (int r = 0; r < 16; ++r) { accO[0][r] *= alpha; accO[1][r] *= alpha; }

        float sum = 0.f;
#pragma unroll
        for (int mt = 0; mt < 2; ++mt)
#pragma unroll
            for (int r = 0; r < 16; ++r) {
                float p = EXP2F(accS[mt][r] - mnew);
                accS[mt][r] = p; sum += p;
            }
        sum += __shfl_xor(sum, 32, 64);
        lsum += sum;

        // P -> Ps[qrow=l31][key], swizzled (in-wave RAW, no barrier)
#pragma unroll
        for (int mt = 0; mt < 2; ++mt)
#pragma unroll
            for (int g = 0; g < 4; ++g) {
                f16x4 ph = { (f16)accS[mt][g*4+0], (f16)accS[mt][g*4+1],
                             (f16)accS[mt][g*4+2], (f16)accS[mt][g*4+3] };
                *(f16x4*)&Ps[wave][(l31 << 6) + ((((mt<<2)+g) ^ l7) << 3) + (hi << 2)] = ph;
            }
        // PV: A = P[qrow][key] (LDS), B = V^T[d][key] (direct global)
        f16x8 af[4];
#pragma unroll
        for (int ks = 0; ks < 4; ++ks)
            af[ks] = *(const f16x8*)&Ps[wave][(l31 << 6) + ((((ks<<1)+hi) ^ l7) << 3)];
#pragma unroll
        for (int ks = 0; ks < 4; ++ks) {
            f16x8 vf0 = *(const f16x8*)(vp0 + ks*16);
            f16x8 vf1 = *(const f16x8*)(vp1 + ks*16);
            accO[0] = MFMA32(af[ks], vf0, accO[0]);
            accO[1] = MFMA32(af[ks], vf1, accO[1]);
        }

        kp  += 64*DD_;
        vp0 += 64;
        vp1 += 64;
    }

    const int b = bh >> 4, h = bh & (HH - 1);
    const float vm0 = vmean[bh*DD_ + l31];
    const float vm1 = vmean[bh*DD_ + 32 + l31];
#pragma unroll
    for (int reg = 0; reg < 16; ++reg) {
        const int qr = (reg & 3) + 8*(reg >> 2) + 4*hi;
        const float lf = __shfl(lsum, qr, 64);
        const float inv = 1.f / lf;
        const int s = q0 + wave*32 + qr;
        f16* op = aout + ((size_t)(b*SS + s))*EE + h*DD_;
        op[l31]      = (f16)(accO[0][reg] * inv + vm0);
        op[32 + l31] = (f16)(accO[1][reg] * inv + vm1);
    }
}

// ---------------------------------------------------------------------------
// Output GEMM, f16 MFMA, global_load_lds + swizzle: y = a@w^T + b (fp32 out)
// ---------------------------------------------------------------------------
__global__ __launch_bounds__(256) void out_gemm_kernel(
    const f16* __restrict__ a, const f16* __restrict__ w,
    const float* __restrict__ bias, float* __restrict__ y)
{
    __shared__ f16 As[128*64];
    __shared__ f16 Bs[128*64];
    const int tid  = threadIdx.x;
    const int wave = tid >> 6, lane = tid & 63;
    const int quad = lane >> 4, l15 = lane & 15;
    const int wm = wave & 1, wn = wave >> 1;
    const int m0 = blockIdx.y << 7, n0 = blockIdx.x << 7;

    f32x4 acc[4][4];
#pragma unroll
    for (int i = 0; i < 4; ++i)
#pragma unroll
        for (int j = 0; j < 4; ++j) acc[i][j] = (f32x4){0.f,0.f,0.f,0.f};

    for (int k0 = 0; k0 < EE; k0 += 64) {
        __syncthreads();
#pragma unroll
        for (int u = 0; u < 4; ++u) {
            const int s = tid + (u << 8);
            const int r = s >> 3;
            const int sc = ((s & 7) ^ (r & 7)) << 3;
            gload16(a + (size_t)(m0 + r)*EE + k0 + sc, &As[s << 3]);
            gload16(w + (size_t)(n0 + r)*EE + k0 + sc, &Bs[s << 3]);
        }
        __syncthreads();
#pragma unroll
        for (int ks = 0; ks < 2; ++ks) {
            f16x8 af[4], bf[4];
#pragma unroll
            for (int i = 0; i < 4; ++i) {
                const int r = wm*64 + i*16 + l15;
                af[i] = *(const f16x8*)&As[(r << 6) + ((((ks<<2)+quad) ^ (l15 & 7)) << 3)];
            }
#pragma unroll
            for (int j = 0; j < 4; ++j) {
                const int r = wn*64 + j*16 + l15;
                bf[j] = *(const f16x8*)&Bs[(r << 6) + ((((ks<<2)+quad) ^ (l15 & 7)) << 3)];
            }
#pragma unroll
            for (int i = 0; i < 4; ++i)
#pragma unroll
                for (int j = 0; j < 4; ++j)
                    acc[i][j] = MFMA16(af[i], bf[j], acc[i][j]);
        }
    }

    float bv[4];
#pragma unroll
    for (int j = 0; j < 4; ++j) bv[j] = bias[n0 + wn*64 + j*16 + l15];
#pragma unroll
    for (int i = 0; i < 4; ++i) {
#pragma unroll
        for (int reg = 0; reg < 4; ++reg) {
            const int m = m0 + wm*64 + i*16 + quad*4 + reg;
#pragma unroll
            for (int j = 0; j < 4; ++j)
                y[(size_t)m*EE + n0 + wn*64 + j*16 + l15] = acc[i][j][reg] + bv[j];
        }
    }
}

// ---------------------------------------------------------------------------
extern "C" void kernel_launch(void* const* d_in, const int* in_sizes, int n_in,
                              void* d_out, int out_size, void* d_ws, size_t ws_size,
                              hipStream_t stream)
{
    const float* x      = (const float*)d_in[0];
    const float* qkv_w  = (const float*)d_in[1];
    const float* qkv_b  = (const float*)d_in[2];
    const float* out_w  = (const float*)d_in[3];
    const float* out_b  = (const float*)d_in[4];
    const float* gates  = (const float*)d_in[5];
    const float* imp    = (const float*)d_in[6];
    const float* thr    = (const float*)d_in[7];
    float* out = (float*)d_out;

    const size_t TSZ = (size_t)BH * SS * DD_;
    f16* x16  = (f16*)d_ws;
    f16* w116 = x16 + (size_t)MROWS * EE;
    f16* w216 = w116 + (size_t)NQKV * EE;
    f16* q16  = w216 + (size_t)EE * EE;
    f16* k16  = q16 + TSZ;
    f16* v16  = k16 + TSZ;
    f16* vtb  = v16 + TSZ;
    f16* aout = vtb + TSZ;
    float* vmean = (float*)(aout + TSZ);

    (void)hipMemsetAsync(vmean, 0, (size_t)BH * DD_ * sizeof(float), stream);

    cvt_kernel<<<(NX4 + NW14 + NW24) / 256, 256, 0, stream>>>(
        x, qkv_w, out_w, x16, w116, w216);

    dim3 g1(NQKV/128, MROWS/128);   // 24 x 32
    qkv_gemm_kernel<<<g1, 256, 0, stream>>>(x16, w116, qkv_b, gates, imp, thr,
                                            q16, k16, v16);
    dim3 g2(SS/64, BH);             // 32 x 32
    vtrans_kernel<<<g2, 256, 0, stream>>>(v16, vtb, vmean);
    attn_kernel<<<512, 256, 0, stream>>>(q16, k16, vtb, vmean, aout);
    dim3 g3(EE/128, MROWS/128);     // 8 x 32
    out_gemm_kernel<<<g3, 256, 0, stream>>>(aout, w216, out_b, out);
}

// Round 10
// 247.592 us; speedup vs baseline: 1.2149x; 1.2149x over previous
//
#include <hip/hip_runtime.h>

#define BB 2
#define SS 2048
#define EE 1024
#define HH 16
#define DD_ 64
#define BH (BB*HH)
#define NQKV (3*EE)
#define MROWS (BB*SS)

typedef _Float16 f16;
typedef _Float16 f16x8 __attribute__((ext_vector_type(8)));
typedef _Float16 f16x4 __attribute__((ext_vector_type(4)));
typedef __fp16 fp16x2 __attribute__((ext_vector_type(2)));
typedef float f32x4 __attribute__((ext_vector_type(4)));
typedef float f32x16 __attribute__((ext_vector_type(16)));

#define MFMA16(a,b,c) __builtin_amdgcn_mfma_f32_16x16x32_f16(a,b,c,0,0,0)
#define MFMA32(a,b,c) __builtin_amdgcn_mfma_f32_32x32x16_f16(a,b,c,0,0,0)
#define EXP2F(x) __builtin_amdgcn_exp2f(x)
#define LOG2E 1.44269504088896f

__device__ __forceinline__ void gload16(const void* g, void* l) {
    __builtin_amdgcn_global_load_lds(
        (const __attribute__((address_space(1))) void*)g,
        (__attribute__((address_space(3))) void*)l, 16, 0, 0);
}

// ---------------------------------------------------------------------------
// fp32 -> f16 one-shot convert: x (4M), qkv_w (3M), out_w (1M) floats.
// ---------------------------------------------------------------------------
#define NX4  1048576
#define NW14  786432
#define NW24  262144
__global__ __launch_bounds__(256) void cvt_kernel(
    const float* __restrict__ x, const float* __restrict__ w1,
    const float* __restrict__ w2, f16* __restrict__ x16,
    f16* __restrict__ w116, f16* __restrict__ w216)
{
    const int i = blockIdx.x * 256 + threadIdx.x;
    const float* src; f16* dst; int off;
    if (i < NX4)              { src = x;  dst = x16;  off = i; }
    else if (i < NX4 + NW14)  { src = w1; dst = w116; off = i - NX4; }
    else                      { src = w2; dst = w216; off = i - NX4 - NW14; }
    float4 v = ((const float4*)src)[off];
    f16x4 h = { (f16)v.x, (f16)v.y, (f16)v.z, (f16)v.w };
    *(f16x4*)(dst + 4*(size_t)off) = h;
}

// ---------------------------------------------------------------------------
// QKV GEMM, f16 MFMA 16x16x32, 128x128 tile, BK=64, 4 waves.
// ---------------------------------------------------------------------------
__global__ __launch_bounds__(256) void qkv_gemm_kernel(
    const f16* __restrict__ x, const f16* __restrict__ w,
    const float* __restrict__ bias, const float* __restrict__ gates,
    const float* __restrict__ imp, const float* __restrict__ thr,
    f16* __restrict__ q16, f16* __restrict__ k16, f16* __restrict__ v16)
{
    __shared__ f16 As[128*64];
    __shared__ f16 Bs[128*64];
    const int tid  = threadIdx.x;
    const int wave = tid >> 6, lane = tid & 63;
    const int quad = lane >> 4, l15 = lane & 15;
    const int wm = wave & 1, wn = wave >> 1;
    const int m0 = blockIdx.y << 7, n0 = blockIdx.x << 7;

    f32x4 acc[4][4];
#pragma unroll
    for (int i = 0; i < 4; ++i)
#pragma unroll
        for (int j = 0; j < 4; ++j) acc[i][j] = (f32x4){0.f,0.f,0.f,0.f};

    for (int k0 = 0; k0 < EE; k0 += 64) {
        __syncthreads();
#pragma unroll
        for (int u = 0; u < 4; ++u) {
            const int s = tid + (u << 8);
            const int r = s >> 3;
            const int sc = ((s & 7) ^ (r & 7)) << 3;
            gload16(x + (size_t)(m0 + r)*EE + k0 + sc, &As[s << 3]);
            gload16(w + (size_t)(n0 + r)*EE + k0 + sc, &Bs[s << 3]);
        }
        __syncthreads();
#pragma unroll
        for (int ks = 0; ks < 2; ++ks) {
            f16x8 af[4], bf[4];
#pragma unroll
            for (int i = 0; i < 4; ++i) {
                const int r = wm*64 + i*16 + l15;
                af[i] = *(const f16x8*)&As[(r << 6) + ((((ks<<2)+quad) ^ (l15 & 7)) << 3)];
            }
#pragma unroll
            for (int j = 0; j < 4; ++j) {
                const int r = wn*64 + j*16 + l15;
                bf[j] = *(const f16x8*)&Bs[(r << 6) + ((((ks<<2)+quad) ^ (l15 & 7)) << 3)];
            }
#pragma unroll
            for (int i = 0; i < 4; ++i)
#pragma unroll
                for (int j = 0; j < 4; ++j)
                    acc[i][j] = MFMA16(af[i], bf[j], acc[i][j]);
        }
    }

    const int nb    = n0 + wn * 64;
    const int which = nb >> 10;
    const int h     = (nb & 1023) >> 6;
    const float gs   = 1.f / (1.f + __expf(-gates[h] * imp[h]));
    float scale = (gs > thr[0]) ? 1.f : 0.f;
    if (which == 0) scale *= LOG2E;
    f16* __restrict__ dst = (which == 0) ? q16 : ((which == 1) ? k16 : v16);
    float bv[4];
#pragma unroll
    for (int j = 0; j < 4; ++j) bv[j] = bias[nb + j*16 + l15];
#pragma unroll
    for (int i = 0; i < 4; ++i) {
#pragma unroll
        for (int reg = 0; reg < 4; ++reg) {
            const int m = m0 + wm*64 + i*16 + quad*4 + reg;
            const int b = m >> 11, s = m & (SS - 1);
            f16* rowp = dst + (((size_t)(b*HH + h))*SS + s)*DD_ + l15;
#pragma unroll
            for (int j = 0; j < 4; ++j)
                rowp[j*16] = (f16)((acc[i][j][reg] + bv[j]) * scale);
        }
    }
}

// ---------------------------------------------------------------------------
// v transpose [B,H,S,D] -> [B,H,D,S] f16, + vmean (fp32 atomic partials)
// ---------------------------------------------------------------------------
__global__ __launch_bounds__(256) void vtrans_kernel(
    const f16* __restrict__ v16, f16* __restrict__ vt, float* __restrict__ vmean)
{
    __shared__ f16 T[64][74];
    const int tid = threadIdx.x;
    const int bh = blockIdx.y, s0 = blockIdx.x << 6;
#pragma unroll
    for (int u = 0; u < 2; ++u) {
        const int f = tid + (u << 8);
        const int r = f >> 3, c = (f & 7) << 3;
        *(f16x8*)&T[r][c] = *(const f16x8*)(v16 + ((size_t)bh*SS + s0 + r)*DD_ + c);
    }
    __syncthreads();
    const int d = tid >> 2, ch = (tid & 3) << 4;
    union { f16 h[16]; f16x8 v8[2]; } t;
    float ps = 0.f;
#pragma unroll
    for (int u = 0; u < 16; ++u) { f16 val = T[ch + u][d]; t.h[u] = val; ps += (float)val; }
    f16* dp = vt + ((size_t)bh*DD_ + d)*SS + s0 + ch;
    *(f16x8*)(dp)     = t.v8[0];
    *(f16x8*)(dp + 8) = t.v8[1];
    ps += __shfl_xor(ps, 1, 64);
    ps += __shfl_xor(ps, 2, 64);
    if ((tid & 3) == 0) atomicAdd(vmean + bh*DD_ + d, ps * (1.f / SS));
}

// ---------------------------------------------------------------------------
// Flash attention v5: r6 occupancy frame (4 waves x 32 q-rows, 512 blocks)
// + BK=128 (half the barriers) + register P^T reshape (no P LDS; r8-verified
// mapping). S^T = K*Q^T; O^T = V^T*P^T; lane owns q-row l31 end-to-end.
// LDS: Ks 128x64 + Vs 64x128 = 32 KB, staged via gload16, swizzled chunks.
// ---------------------------------------------------------------------------
__global__ __launch_bounds__(256) void attn_kernel(
    const f16* __restrict__ q16, const f16* __restrict__ k16,
    const f16* __restrict__ vt, const float* __restrict__ vmean,
    f16* __restrict__ aout)
{
    __shared__ f16 Ks[128*64];         // [key][d], swizzled 16B chunks (8/row)
    __shared__ f16 Vs[64*128];         // [d][key], swizzled 16B chunks (16/row)
    const int tid  = threadIdx.x;
    const int wave = tid >> 6, lane = tid & 63;
    const int l31 = lane & 31, hi = lane >> 5;
    const int bh = blockIdx.y, q0 = blockIdx.x << 7;   // 128 q-rows/block
    const f16* qb = q16 + (size_t)bh * SS * DD_;
    const f16* kb = k16 + (size_t)bh * SS * DD_;
    const f16* vb = vt  + (size_t)bh * DD_ * SS;

    // Q frags (B-operand for S^T): B[k=ks*16+hi*8+j][n=qrow=l31]
    f16x8 qf[4];
#pragma unroll
    for (int ks = 0; ks < 4; ++ks)
        qf[ks] = *(const f16x8*)(qb + (size_t)(q0 + wave*32 + l31)*DD_ + ks*16 + hi*8);

    f32x16 accO[2];                    // O^T accum: rows=d, cols=qrow
#pragma unroll
    for (int dt = 0; dt < 2; ++dt)
#pragma unroll
        for (int r = 0; r < 16; ++r) accO[dt][r] = 0.f;
    float M = -1.0e30f, lsum = 0.f;

    for (int kt = 0; kt < SS; kt += 128) {
        __syncthreads();
        // stage K[kt..kt+128)x64 (1024 chunks) + V^T 64x[kt..kt+128) (1024)
#pragma unroll
        for (int u = 0; u < 4; ++u) {
            const int s = tid + (u << 8);
            const int rk = s >> 3, ck = s & 7;
            gload16(kb + (size_t)(kt + rk)*DD_ + (((ck ^ rk) & 7) << 3), &Ks[s << 3]);
            const int rv = s >> 4, cv = s & 15;
            const int cvp = (cv & 8) | ((cv ^ rv) & 7);
            gload16(vb + (size_t)rv*SS + kt + (cvp << 3), &Vs[s << 3]);
        }
        __syncthreads();

        // S^T[key][qrow]: A = K rows, B = Q^T.  mt over 4 key-32-chunks.
        f32x16 accS[4];
#pragma unroll
        for (int mt = 0; mt < 4; ++mt)
#pragma unroll
            for (int r = 0; r < 16; ++r) accS[mt][r] = 0.f;
#pragma unroll
        for (int ks = 0; ks < 4; ++ks)
#pragma unroll
            for (int mt = 0; mt < 4; ++mt) {
                const int r = mt*32 + l31;
                const int c = (ks << 1) + hi;              // logical d-chunk
                f16x8 kf = *(const f16x8*)&Ks[(r << 6) + (((c ^ r) & 7) << 3)];
                accS[mt] = MFMA32(kf, qf[ks], accS[mt]);
            }

        // wave-uniform tile max (6-stage butterfly)
        float mx = -1.0e30f;
#pragma unroll
        for (int mt = 0; mt < 4; ++mt)
#pragma unroll
            for (int r = 0; r < 16; ++r) mx = fmaxf(mx, accS[mt][r]);
        mx = fmaxf(mx, __shfl_xor(mx, 1, 64));
        mx = fmaxf(mx, __shfl_xor(mx, 2, 64));
        mx = fmaxf(mx, __shfl_xor(mx, 4, 64));
        mx = fmaxf(mx, __shfl_xor(mx, 8, 64));
        mx = fmaxf(mx, __shfl_xor(mx, 16, 64));
        mx = fmaxf(mx, __shfl_xor(mx, 32, 64));
        const float mnew = fmaxf(M, mx);
        const float alpha = EXP2F(M - mnew);
        M = mnew;
        lsum *= alpha;
#pragma unroll
        for (int r = 0; r < 16; ++r) { accO[0][r] *= alpha; accO[1][r] *= alpha; }

        // p = exp2(s - M); lane sums its 64 scores of q-row l31
        float sum = 0.f;
#pragma unroll
        for (int mt = 0; mt < 4; ++mt)
#pragma unroll
            for (int r = 0; r < 16; ++r) {
                float p = EXP2F(accS[mt][r] - mnew);
                accS[mt][r] = p; sum += p;
            }
        sum += __shfl_xor(sum, 32, 64);
        lsum += sum;

        // pack P to f16x2 pairs (ints) for the register reshape
        int pki[4][8];
#pragma unroll
        for (int mt = 0; mt < 4; ++mt)
#pragma unroll
            for (int t = 0; t < 8; ++t) {
                union { fp16x2 h; int i; } c;
                c.h = __builtin_amdgcn_cvt_pkrtz(accS[mt][2*t], accS[mt][2*t+1]);
                pki[mt][t] = c.i;
            }

        // PV: O^T = V^T * P^T.  ks 0..7 over 128 keys; B-frag via shfl_xor(32).
#pragma unroll
        for (int ks = 0; ks < 8; ++ks) {
            const int mt = ks >> 1;
            const int bidx = (ks & 1) << 2;
            const int a0 = pki[mt][bidx+0], a1 = pki[mt][bidx+1];
            const int b0 = pki[mt][bidx+2], b1 = pki[mt][bidx+3];
            const int s0 = hi ? a0 : b0;
            const int s1 = hi ? a1 : b1;
            const int r0 = __shfl_xor(s0, 32, 64);
            const int r1 = __shfl_xor(s1, 32, 64);
            union { int i[4]; f16x8 h; } u;
            u.i[0] = hi ? r0 : a0;
            u.i[1] = hi ? r1 : a1;
            u.i[2] = hi ? b0 : r0;
            u.i[3] = hi ? b1 : r1;
            const int c = (ks << 1) + hi;                  // logical key-chunk
#pragma unroll
            for (int dt = 0; dt < 2; ++dt) {
                const int r = dt*32 + l31;
                const int cp = (c & 8) | ((c ^ r) & 7);
                f16x8 vf = *(const f16x8*)&Vs[(r << 7) + (cp << 3)];
                accO[dt] = MFMA32(vf, u.h, accO[dt]);
            }
        }
    }

    // epilogue: lane owns q-row l31 (col of O^T) -> per-lane 1/lsum.
    // O^T row d = dt*32 + 8g + 4hi + (reg&3)
    const int b = bh >> 4, h = bh & (HH - 1);
    const float inv = 1.f / lsum;
    const int s = q0 + wave*32 + l31;
    f16* op = aout + ((size_t)(b*SS + s))*EE + h*DD_;
#pragma unroll
    for (int dt = 0; dt < 2; ++dt)
#pragma unroll
        for (int g = 0; g < 4; ++g) {
            const int d0 = dt*32 + 8*g + 4*hi;
            float4 vm = *(const float4*)(vmean + bh*DD_ + d0);
            f16x4 o = { (f16)(accO[dt][4*g+0]*inv + vm.x),
                        (f16)(accO[dt][4*g+1]*inv + vm.y),
                        (f16)(accO[dt][4*g+2]*inv + vm.z),
                        (f16)(accO[dt][4*g+3]*inv + vm.w) };
            *(f16x4*)(op + d0) = o;
        }
}

// ---------------------------------------------------------------------------
// Output GEMM, f16 MFMA, global_load_lds + swizzle: y = a@w^T + b (fp32 out)
// ---------------------------------------------------------------------------
__global__ __launch_bounds__(256) void out_gemm_kernel(
    const f16* __restrict__ a, const f16* __restrict__ w,
    const float* __restrict__ bias, float* __restrict__ y)
{
    __shared__ f16 As[128*64];
    __shared__ f16 Bs[128*64];
    const int tid  = threadIdx.x;
    const int wave = tid >> 6, lane = tid & 63;
    const int quad = lane >> 4, l15 = lane & 15;
    const int wm = wave & 1, wn = wave >> 1;
    const int m0 = blockIdx.y << 7, n0 = blockIdx.x << 7;

    f32x4 acc[4][4];
#pragma unroll
    for (int i = 0; i < 4; ++i)
#pragma unroll
        for (int j = 0; j < 4; ++j) acc[i][j] = (f32x4){0.f,0.f,0.f,0.f};

    for (int k0 = 0; k0 < EE; k0 += 64) {
        __syncthreads();
#pragma unroll
        for (int u = 0; u < 4; ++u) {
            const int s = tid + (u << 8);
            const int r = s >> 3;
            const int sc = ((s & 7) ^ (r & 7)) << 3;
            gload16(a + (size_t)(m0 + r)*EE + k0 + sc, &As[s << 3]);
            gload16(w + (size_t)(n0 + r)*EE + k0 + sc, &Bs[s << 3]);
        }
        __syncthreads();
#pragma unroll
        for (int ks = 0; ks < 2; ++ks) {
            f16x8 af[4], bf[4];
#pragma unroll
            for (int i = 0; i < 4; ++i) {
                const int r = wm*64 + i*16 + l15;
                af[i] = *(const f16x8*)&As[(r << 6) + ((((ks<<2)+quad) ^ (l15 & 7)) << 3)];
            }
#pragma unroll
            for (int j = 0; j < 4; ++j) {
                const int r = wn*64 + j*16 + l15;
                bf[j] = *(const f16x8*)&Bs[(r << 6) + ((((ks<<2)+quad) ^ (l15 & 7)) << 3)];
            }
#pragma unroll
            for (int i = 0; i < 4; ++i)
#pragma unroll
                for (int j = 0; j < 4; ++j)
                    acc[i][j] = MFMA16(af[i], bf[j], acc[i][j]);
        }
    }

    float bv[4];
#pragma unroll
    for (int j = 0; j < 4; ++j) bv[j] = bias[n0 + wn*64 + j*16 + l15];
#pragma unroll
    for (int i = 0; i < 4; ++i) {
#pragma unroll
        for (int reg = 0; reg < 4; ++reg) {
            const int m = m0 + wm*64 + i*16 + quad*4 + reg;
#pragma unroll
            for (int j = 0; j < 4; ++j)
                y[(size_t)m*EE + n0 + wn*64 + j*16 + l15] = acc[i][j][reg] + bv[j];
        }
    }
}

// ---------------------------------------------------------------------------
extern "C" void kernel_launch(void* const* d_in, const int* in_sizes, int n_in,
                              void* d_out, int out_size, void* d_ws, size_t ws_size,
                              hipStream_t stream)
{
    const float* x      = (const float*)d_in[0];
    const float* qkv_w  = (const float*)d_in[1];
    const float* qkv_b  = (const float*)d_in[2];
    const float* out_w  = (const float*)d_in[3];
    const float* out_b  = (const float*)d_in[4];
    const float* gates  = (const float*)d_in[5];
    const float* imp    = (const float*)d_in[6];
    const float* thr    = (const float*)d_in[7];
    float* out = (float*)d_out;

    const size_t TSZ = (size_t)BH * SS * DD_;
    f16* x16  = (f16*)d_ws;
    f16* w116 = x16 + (size_t)MROWS * EE;
    f16* w216 = w116 + (size_t)NQKV * EE;
    f16* q16  = w216 + (size_t)EE * EE;
    f16* k16  = q16 + TSZ;
    f16* v16  = k16 + TSZ;
    f16* vtb  = v16 + TSZ;
    f16* aout = vtb + TSZ;
    float* vmean = (float*)(aout + TSZ);

    (void)hipMemsetAsync(vmean, 0, (size_t)BH * DD_ * sizeof(float), stream);

    cvt_kernel<<<(NX4 + NW14 + NW24) / 256, 256, 0, stream>>>(
        x, qkv_w, out_w, x16, w116, w216);

    dim3 g1(NQKV/128, MROWS/128);   // 24 x 32
    qkv_gemm_kernel<<<g1, 256, 0, stream>>>(x16, w116, qkv_b, gates, imp, thr,
                                            q16, k16, v16);
    dim3 g2(SS/64, BH);             // 32 x 32
    vtrans_kernel<<<g2, 256, 0, stream>>>(v16, vtb, vmean);
    dim3 g2a(SS/128, BH);           // 16 x 32 = 512 blocks (2/CU)
    attn_kernel<<<g2a, 256, 0, stream>>>(q16, k16, vtb, vmean, aout);
    dim3 g3(EE/128, MROWS/128);     // 8 x 32
    out_gemm_kernel<<<g3, 256, 0, stream>>>(aout, w216, out_b, out);
}

// Round 11
// 222.364 us; speedup vs baseline: 1.3527x; 1.1135x over previous
//
#include <hip/hip_runtime.h>

#define BB 2
#define SS 2048
#define EE 1024
#define HH 16
#define DD_ 64
#define BH (BB*HH)
#define NQKV (3*EE)
#define MROWS (BB*SS)

typedef _Float16 f16;
typedef _Float16 f16x8 __attribute__((ext_vector_type(8)));
typedef _Float16 f16x4 __attribute__((ext_vector_type(4)));
typedef __fp16 fp16x2 __attribute__((ext_vector_type(2)));
typedef float f32x4 __attribute__((ext_vector_type(4)));
typedef float f32x16 __attribute__((ext_vector_type(16)));

#define MFMA16(a,b,c) __builtin_amdgcn_mfma_f32_16x16x32_f16(a,b,c,0,0,0)
#define MFMA32(a,b,c) __builtin_amdgcn_mfma_f32_32x32x16_f16(a,b,c,0,0,0)
#define EXP2F(x) __builtin_amdgcn_exp2f(x)
#define LOG2E 1.44269504088896f

__device__ __forceinline__ void gload16(const void* g, void* l) {
    __builtin_amdgcn_global_load_lds(
        (const __attribute__((address_space(1))) void*)g,
        (__attribute__((address_space(3))) void*)l, 16, 0, 0);
}

// ---------------------------------------------------------------------------
// fp32 -> f16 one-shot convert: x (4M), qkv_w (3M), out_w (1M) floats.
// ---------------------------------------------------------------------------
#define NX4  1048576
#define NW14  786432
#define NW24  262144
__global__ __launch_bounds__(256) void cvt_kernel(
    const float* __restrict__ x, const float* __restrict__ w1,
    const float* __restrict__ w2, f16* __restrict__ x16,
    f16* __restrict__ w116, f16* __restrict__ w216)
{
    const int i = blockIdx.x * 256 + threadIdx.x;
    const float* src; f16* dst; int off;
    if (i < NX4)              { src = x;  dst = x16;  off = i; }
    else if (i < NX4 + NW14)  { src = w1; dst = w116; off = i - NX4; }
    else                      { src = w2; dst = w216; off = i - NX4 - NW14; }
    float4 v = ((const float4*)src)[off];
    f16x4 h = { (f16)v.x, (f16)v.y, (f16)v.z, (f16)v.w };
    *(f16x4*)(dst + 4*(size_t)off) = h;
}

// ---------------------------------------------------------------------------
// QKV GEMM, f16 MFMA 16x16x32, 128x128 tile, BK=64, 4 waves.
// ---------------------------------------------------------------------------
__global__ __launch_bounds__(256) void qkv_gemm_kernel(
    const f16* __restrict__ x, const f16* __restrict__ w,
    const float* __restrict__ bias, const float* __restrict__ gates,
    const float* __restrict__ imp, const float* __restrict__ thr,
    f16* __restrict__ q16, f16* __restrict__ k16, f16* __restrict__ v16)
{
    __shared__ f16 As[128*64];
    __shared__ f16 Bs[128*64];
    const int tid  = threadIdx.x;
    const int wave = tid >> 6, lane = tid & 63;
    const int quad = lane >> 4, l15 = lane & 15;
    const int wm = wave & 1, wn = wave >> 1;
    const int m0 = blockIdx.y << 7, n0 = blockIdx.x << 7;

    f32x4 acc[4][4];
#pragma unroll
    for (int i = 0; i < 4; ++i)
#pragma unroll
        for (int j = 0; j < 4; ++j) acc[i][j] = (f32x4){0.f,0.f,0.f,0.f};

    for (int k0 = 0; k0 < EE; k0 += 64) {
        __syncthreads();
#pragma unroll
        for (int u = 0; u < 4; ++u) {
            const int s = tid + (u << 8);
            const int r = s >> 3;
            const int sc = ((s & 7) ^ (r & 7)) << 3;
            gload16(x + (size_t)(m0 + r)*EE + k0 + sc, &As[s << 3]);
            gload16(w + (size_t)(n0 + r)*EE + k0 + sc, &Bs[s << 3]);
        }
        __syncthreads();
#pragma unroll
        for (int ks = 0; ks < 2; ++ks) {
            f16x8 af[4], bf[4];
#pragma unroll
            for (int i = 0; i < 4; ++i) {
                const int r = wm*64 + i*16 + l15;
                af[i] = *(const f16x8*)&As[(r << 6) + ((((ks<<2)+quad) ^ (l15 & 7)) << 3)];
            }
#pragma unroll
            for (int j = 0; j < 4; ++j) {
                const int r = wn*64 + j*16 + l15;
                bf[j] = *(const f16x8*)&Bs[(r << 6) + ((((ks<<2)+quad) ^ (l15 & 7)) << 3)];
            }
#pragma unroll
            for (int i = 0; i < 4; ++i)
#pragma unroll
                for (int j = 0; j < 4; ++j)
                    acc[i][j] = MFMA16(af[i], bf[j], acc[i][j]);
        }
    }

    const int nb    = n0 + wn * 64;
    const int which = nb >> 10;
    const int h     = (nb & 1023) >> 6;
    const float gs   = 1.f / (1.f + __expf(-gates[h] * imp[h]));
    float scale = (gs > thr[0]) ? 1.f : 0.f;
    if (which == 0) scale *= LOG2E;
    f16* __restrict__ dst = (which == 0) ? q16 : ((which == 1) ? k16 : v16);
    float bv[4];
#pragma unroll
    for (int j = 0; j < 4; ++j) bv[j] = bias[nb + j*16 + l15];
#pragma unroll
    for (int i = 0; i < 4; ++i) {
#pragma unroll
        for (int reg = 0; reg < 4; ++reg) {
            const int m = m0 + wm*64 + i*16 + quad*4 + reg;
            const int b = m >> 11, s = m & (SS - 1);
            f16* rowp = dst + (((size_t)(b*HH + h))*SS + s)*DD_ + l15;
#pragma unroll
            for (int j = 0; j < 4; ++j)
                rowp[j*16] = (f16)((acc[i][j][reg] + bv[j]) * scale);
        }
    }
}

// ---------------------------------------------------------------------------
// v transpose [B,H,S,D] -> [B,H,D,S] f16, + vmean (fp32 atomic partials)
// ---------------------------------------------------------------------------
__global__ __launch_bounds__(256) void vtrans_kernel(
    const f16* __restrict__ v16, f16* __restrict__ vt, float* __restrict__ vmean)
{
    __shared__ f16 T[64][74];
    const int tid = threadIdx.x;
    const int bh = blockIdx.y, s0 = blockIdx.x << 6;
#pragma unroll
    for (int u = 0; u < 2; ++u) {
        const int f = tid + (u << 8);
        const int r = f >> 3, c = (f & 7) << 3;
        *(f16x8*)&T[r][c] = *(const f16x8*)(v16 + ((size_t)bh*SS + s0 + r)*DD_ + c);
    }
    __syncthreads();
    const int d = tid >> 2, ch = (tid & 3) << 4;
    union { f16 h[16]; f16x8 v8[2]; } t;
    float ps = 0.f;
#pragma unroll
    for (int u = 0; u < 16; ++u) { f16 val = T[ch + u][d]; t.h[u] = val; ps += (float)val; }
    f16* dp = vt + ((size_t)bh*DD_ + d)*SS + s0 + ch;
    *(f16x8*)(dp)     = t.v8[0];
    *(f16x8*)(dp + 8) = t.v8[1];
    ps += __shfl_xor(ps, 1, 64);
    ps += __shfl_xor(ps, 2, 64);
    if ((tid & 3) == 0) atomicAdd(vmean + bh*DD_ + d, ps * (1.f / SS));
}

// ---------------------------------------------------------------------------
// Flash attention v6: n=2 q-blocking (64 q-rows/wave -> every K/V fragment
// read feeds 2 MFMAs) + key-split (each block does half the keys, fp32
// partials combined by combine_kernel) to keep 2 blocks/CU resident.
// 4 waves x 64 q = 256 q-rows/block; grid 8 qc x 2 kp x 32 bh = 512 blocks.
// Register P^T reshape (r8 HW-verified mapping, no P LDS). LDS 16 KB.
// ---------------------------------------------------------------------------
__global__ __launch_bounds__(256, 2) void attn_kernel(
    const f16* __restrict__ q16, const f16* __restrict__ k16,
    const f16* __restrict__ vt,
    float* __restrict__ opart, float* __restrict__ mlpart)
{
    __shared__ f16 Ks[64*64];          // [key][d], swizzled source chunks
    __shared__ f16 Vs[64*64];          // [d][key], swizzled
    const int tid  = threadIdx.x;
    const int wave = tid >> 6, lane = tid & 63;
    const int l31 = lane & 31, hi = lane >> 5, l7 = lane & 7;
    const int bh = blockIdx.y;
    const int qc = blockIdx.x >> 1;    // 0..7
    const int kp = blockIdx.x & 1;     // key part 0/1
    const int q0 = qc << 8;            // 256 q-rows/block
    const int k0 = kp << 10;           // 1024 keys/part

    const f16* qb = q16 + (size_t)bh * SS * DD_;
    const f16* kb = k16 + (size_t)bh * SS * DD_;
    const f16* vb = vt  + (size_t)bh * DD_ * SS;

    // Q frags (B-operand): chunk n covers q-rows q0+wave*64+n*32+l31
    f16x8 qf[2][4];
#pragma unroll
    for (int n = 0; n < 2; ++n)
#pragma unroll
        for (int ks = 0; ks < 4; ++ks)
            qf[n][ks] = *(const f16x8*)(qb +
                (size_t)(q0 + wave*64 + n*32 + l31)*DD_ + ks*16 + hi*8);

    f32x16 accO[2][2];                 // [n][dt] O^T accum (col = qrow)
#pragma unroll
    for (int n = 0; n < 2; ++n)
#pragma unroll
        for (int dt = 0; dt < 2; ++dt)
#pragma unroll
            for (int r = 0; r < 16; ++r) accO[n][dt][r] = 0.f;
    float M = -1.0e30f;
    float lsum[2] = {0.f, 0.f};

    // staging (r6 pattern): thread owns chunks tid, tid+256 of each tile
    const int r0 = tid >> 3, r1 = r0 + 32, cc = tid & 7;
    const int sc0 = (cc ^ (r0 & 7)) << 3;
    const int sc1 = (cc ^ (r1 & 7)) << 3;

    for (int kt = k0; kt < k0 + 1024; kt += 64) {
        __syncthreads();
        gload16(kb + (size_t)(kt + r0)*DD_ + sc0, &Ks[tid << 3]);
        gload16(kb + (size_t)(kt + r1)*DD_ + sc1, &Ks[(tid + 256) << 3]);
        gload16(vb + (size_t)r0*SS + kt + sc0,    &Vs[tid << 3]);
        gload16(vb + (size_t)r1*SS + kt + sc1,    &Vs[(tid + 256) << 3]);
        __syncthreads();

        // S^T[key][qrow]: A = K rows, B = Q^T; kf shared across n
        f32x16 accS[2][2];
#pragma unroll
        for (int n = 0; n < 2; ++n)
#pragma unroll
            for (int mt = 0; mt < 2; ++mt)
#pragma unroll
                for (int r = 0; r < 16; ++r) accS[n][mt][r] = 0.f;
#pragma unroll
        for (int ks = 0; ks < 4; ++ks)
#pragma unroll
            for (int mt = 0; mt < 2; ++mt) {
                f16x8 kf = *(const f16x8*)&Ks[((mt*32 + l31) << 6) +
                                              ((((ks<<1)+hi) ^ l7) << 3)];
#pragma unroll
                for (int n = 0; n < 2; ++n)
                    accS[n][mt] = MFMA32(kf, qf[n][ks], accS[n][mt]);
            }

        // wave-uniform tile max over both chunks
        float mx = -1.0e30f;
#pragma unroll
        for (int n = 0; n < 2; ++n)
#pragma unroll
            for (int mt = 0; mt < 2; ++mt)
#pragma unroll
                for (int r = 0; r < 16; ++r) mx = fmaxf(mx, accS[n][mt][r]);
        mx = fmaxf(mx, __shfl_xor(mx, 1, 64));
        mx = fmaxf(mx, __shfl_xor(mx, 2, 64));
        mx = fmaxf(mx, __shfl_xor(mx, 4, 64));
        mx = fmaxf(mx, __shfl_xor(mx, 8, 64));
        mx = fmaxf(mx, __shfl_xor(mx, 16, 64));
        mx = fmaxf(mx, __shfl_xor(mx, 32, 64));
        const float mnew = fmaxf(M, mx);
        const float alpha = EXP2F(M - mnew);
        M = mnew;
#pragma unroll
        for (int n = 0; n < 2; ++n) {
            lsum[n] *= alpha;
#pragma unroll
            for (int r = 0; r < 16; ++r) { accO[n][0][r] *= alpha; accO[n][1][r] *= alpha; }
        }

        // p = exp2(s - M); per-row sums (lane + its hi-partner own q-row l31)
#pragma unroll
        for (int n = 0; n < 2; ++n) {
            float sum = 0.f;
#pragma unroll
            for (int mt = 0; mt < 2; ++mt)
#pragma unroll
                for (int r = 0; r < 16; ++r) {
                    float p = EXP2F(accS[n][mt][r] - mnew);
                    accS[n][mt][r] = p; sum += p;
                }
            sum += __shfl_xor(sum, 32, 64);
            lsum[n] += sum;
        }

        // pack P to f16x2 pairs (ints) for register reshape
        int pki[2][2][8];
#pragma unroll
        for (int n = 0; n < 2; ++n)
#pragma unroll
            for (int mt = 0; mt < 2; ++mt)
#pragma unroll
                for (int t = 0; t < 8; ++t) {
                    union { fp16x2 h; int i; } c;
                    c.h = __builtin_amdgcn_cvt_pkrtz(accS[n][mt][2*t], accS[n][mt][2*t+1]);
                    pki[n][mt][t] = c.i;
                }

        // PV: O^T = V^T * P^T (r8-verified B-frag mapping); vf shared across n
#pragma unroll
        for (int ks = 0; ks < 4; ++ks) {
            const int mt = ks >> 1;
            const int bidx = (ks & 1) << 2;
            f16x8 pf[2];
#pragma unroll
            for (int n = 0; n < 2; ++n) {
                const int a0 = pki[n][mt][bidx+0], a1 = pki[n][mt][bidx+1];
                const int b0 = pki[n][mt][bidx+2], b1 = pki[n][mt][bidx+3];
                const int s0 = hi ? a0 : b0;
                const int s1 = hi ? a1 : b1;
                const int r0x = __shfl_xor(s0, 32, 64);
                const int r1x = __shfl_xor(s1, 32, 64);
                union { int i[4]; f16x8 h; } u;
                u.i[0] = hi ? r0x : a0;
                u.i[1] = hi ? r1x : a1;
                u.i[2] = hi ? b0 : r0x;
                u.i[3] = hi ? b1 : r1x;
                pf[n] = u.h;
            }
#pragma unroll
            for (int dt = 0; dt < 2; ++dt) {
                f16x8 vf = *(const f16x8*)&Vs[((dt*32 + l31) << 6) +
                                              ((((ks<<1)+hi) ^ l7) << 3)];
#pragma unroll
                for (int n = 0; n < 2; ++n)
                    accO[n][dt] = MFMA32(vf, pf[n], accO[n][dt]);
            }
        }
    }

    // store fp32 partials: O^T (un-normalized), M, lsum per q-row
#pragma unroll
    for (int n = 0; n < 2; ++n) {
        const int s = q0 + wave*64 + n*32 + l31;
        const size_t rowi = (size_t)kp*BH*SS + (size_t)bh*SS + s;
        float* ob = opart + (rowi << 6);
#pragma unroll
        for (int dt = 0; dt < 2; ++dt)
#pragma unroll
            for (int g = 0; g < 4; ++g) {
                const int d0 = dt*32 + 8*g + 4*hi;
                float4 o = { accO[n][dt][4*g+0], accO[n][dt][4*g+1],
                             accO[n][dt][4*g+2], accO[n][dt][4*g+3] };
                *(float4*)(ob + d0) = o;
            }
        if (hi == 0) {
            float2 ml = { M, lsum[n] };
            *(float2*)(mlpart + rowi*2) = ml;
        }
    }
}

// ---------------------------------------------------------------------------
// Combine the two key-part partials: out = sum_p(O_p a_p) / sum_p(l_p a_p)
// + vmean, write f16 [B,S,E].
// ---------------------------------------------------------------------------
__global__ __launch_bounds__(256) void combine_kernel(
    const float* __restrict__ opart, const float* __restrict__ mlpart,
    const float* __restrict__ vmean, f16* __restrict__ aout)
{
    const int t = blockIdx.x * 256 + threadIdx.x;  // 0 .. 262143
    const int row = t >> 2;                        // bh*SS + s
    const int dc = (t & 3) << 4;
    const int bh = row >> 11, s = row & (SS - 1);
    const int b = bh >> 4, h = bh & (HH - 1);
    const float2 ml0 = ((const float2*)mlpart)[row];
    const float2 ml1 = ((const float2*)mlpart)[BH*SS + row];
    const float mx = fmaxf(ml0.x, ml1.x);
    const float a0 = EXP2F(ml0.x - mx), a1 = EXP2F(ml1.x - mx);
    const float inv = 1.f / (ml0.y*a0 + ml1.y*a1);
    const float* o0 = opart + ((size_t)row << 6) + dc;
    const float* o1 = o0 + ((size_t)(BH*SS) << 6);
    f16* op = aout + ((size_t)(b*SS + s))*EE + h*DD_ + dc;
#pragma unroll
    for (int j = 0; j < 4; ++j) {
        float4 v0 = ((const float4*)o0)[j];
        float4 v1 = ((const float4*)o1)[j];
        float4 vm = *(const float4*)(vmean + bh*DD_ + dc + 4*j);
        f16x4 o = { (f16)((v0.x*a0 + v1.x*a1)*inv + vm.x),
                    (f16)((v0.y*a0 + v1.y*a1)*inv + vm.y),
                    (f16)((v0.z*a0 + v1.z*a1)*inv + vm.z),
                    (f16)((v0.w*a0 + v1.w*a1)*inv + vm.w) };
        *(f16x4*)(op + 4*j) = o;
    }
}

// ---------------------------------------------------------------------------
// Output GEMM, f16 MFMA, global_load_lds + swizzle: y = a@w^T + b (fp32 out)
// ---------------------------------------------------------------------------
__global__ __launch_bounds__(256) void out_gemm_kernel(
    const f16* __restrict__ a, const f16* __restrict__ w,
    const float* __restrict__ bias, float* __restrict__ y)
{
    __shared__ f16 As[128*64];
    __shared__ f16 Bs[128*64];
    const int tid  = threadIdx.x;
    const int wave = tid >> 6, lane = tid & 63;
    const int quad = lane >> 4, l15 = lane & 15;
    const int wm = wave & 1, wn = wave >> 1;
    const int m0 = blockIdx.y << 7, n0 = blockIdx.x << 7;

    f32x4 acc[4][4];
#pragma unroll
    for (int i = 0; i < 4; ++i)
#pragma unroll
        for (int j = 0; j < 4; ++j) acc[i][j] = (f32x4){0.f,0.f,0.f,0.f};

    for (int k0 = 0; k0 < EE; k0 += 64) {
        __syncthreads();
#pragma unroll
        for (int u = 0; u < 4; ++u) {
            const int s = tid + (u << 8);
            const int r = s >> 3;
            const int sc = ((s & 7) ^ (r & 7)) << 3;
            gload16(a + (size_t)(m0 + r)*EE + k0 + sc, &As[s << 3]);
            gload16(w + (size_t)(n0 + r)*EE + k0 + sc, &Bs[s << 3]);
        }
        __syncthreads();
#pragma unroll
        for (int ks = 0; ks < 2; ++ks) {
            f16x8 af[4], bf[4];
#pragma unroll
            for (int i = 0; i < 4; ++i) {
                const int r = wm*64 + i*16 + l15;
                af[i] = *(const f16x8*)&As[(r << 6) + ((((ks<<2)+quad) ^ (l15 & 7)) << 3)];
            }
#pragma unroll
            for (int j = 0; j < 4; ++j) {
                const int r = wn*64 + j*16 + l15;
                bf[j] = *(const f16x8*)&Bs[(r << 6) + ((((ks<<2)+quad) ^ (l15 & 7)) << 3)];
            }
#pragma unroll
            for (int i = 0; i < 4; ++i)
#pragma unroll
                for (int j = 0; j < 4; ++j)
                    acc[i][j] = MFMA16(af[i], bf[j], acc[i][j]);
        }
    }

    float bv[4];
#pragma unroll
    for (int j = 0; j < 4; ++j) bv[j] = bias[n0 + wn*64 + j*16 + l15];
#pragma unroll
    for (int i = 0; i < 4; ++i) {
#pragma unroll
        for (int reg = 0; reg < 4; ++reg) {
            const int m = m0 + wm*64 + i*16 + quad*4 + reg;
#pragma unroll
            for (int j = 0; j < 4; ++j)
                y[(size_t)m*EE + n0 + wn*64 + j*16 + l15] = acc[i][j][reg] + bv[j];
        }
    }
}

// ---------------------------------------------------------------------------
extern "C" void kernel_launch(void* const* d_in, const int* in_sizes, int n_in,
                              void* d_out, int out_size, void* d_ws, size_t ws_size,
                              hipStream_t stream)
{
    const float* x      = (const float*)d_in[0];
    const float* qkv_w  = (const float*)d_in[1];
    const float* qkv_b  = (const float*)d_in[2];
    const float* out_w  = (const float*)d_in[3];
    const float* out_b  = (const float*)d_in[4];
    const float* gates  = (const float*)d_in[5];
    const float* imp    = (const float*)d_in[6];
    const float* thr    = (const float*)d_in[7];
    float* out = (float*)d_out;

    const size_t TSZ = (size_t)BH * SS * DD_;
    f16* x16  = (f16*)d_ws;
    f16* w116 = x16 + (size_t)MROWS * EE;
    f16* w216 = w116 + (size_t)NQKV * EE;
    f16* q16  = w216 + (size_t)EE * EE;
    f16* k16  = q16 + TSZ;
    f16* v16  = k16 + TSZ;
    f16* vtb  = v16 + TSZ;
    f16* aout = vtb + TSZ;
    float* vmean  = (float*)(aout + TSZ);               // BH*DD_ floats
    float* opart  = vmean + (size_t)BH * DD_;            // 2*BH*SS*DD_ floats
    float* mlpart = opart + 2*(size_t)BH*SS*DD_;         // 2*BH*SS*2 floats

    (void)hipMemsetAsync(vmean, 0, (size_t)BH * DD_ * sizeof(float), stream);

    cvt_kernel<<<(NX4 + NW14 + NW24) / 256, 256, 0, stream>>>(
        x, qkv_w, out_w, x16, w116, w216);

    dim3 g1(NQKV/128, MROWS/128);   // 24 x 32
    qkv_gemm_kernel<<<g1, 256, 0, stream>>>(x16, w116, qkv_b, gates, imp, thr,
                                            q16, k16, v16);
    dim3 g2(SS/64, BH);             // 32 x 32
    vtrans_kernel<<<g2, 256, 0, stream>>>(v16, vtb, vmean);
    dim3 g2a(16, BH);               // (8 qc x 2 kp) x 32 bh = 512 blocks
    attn_kernel<<<g2a, 256, 0, stream>>>(q16, k16, vtb, opart, mlpart);
    combine_kernel<<<(BH*SS*4)/256, 256, 0, stream>>>(opart, mlpart, vmean, aout);
    dim3 g3(EE/128, MROWS/128);     // 8 x 32
    out_gemm_kernel<<<g3, 256, 0, stream>>>(aout, w216, out_b, out);
}